// Round 1
// baseline (180.049 us; speedup 1.0000x reference)
//
#include <hip/hip_runtime.h>

#define KF 7
#define HW 28
#define NPIX 784   // 28*28
#define NB 512
#define NF 8

// ---------------------------------------------------------------------------
// SMorph stage 0: y1[f,b,p] = smorph(x[b], w[f,0], alpha[f,0])
// One block per (f,b) image. Image staged in LDS.
// SAME zero padding: OOB taps contribute z = 0 + w(s) and stay in softmax.
// ---------------------------------------------------------------------------
__global__ __launch_bounds__(256) void smorph1_kernel(
    const float* __restrict__ x,      // [512, 784]
    const float* __restrict__ w,      // [8, 2, 49]
    const float* __restrict__ alpha,  // [8, 2]
    float* __restrict__ y1)           // [8, 512, 784]
{
    __shared__ float img[NPIX];
    __shared__ float wsh[49];
    const int fb = blockIdx.x;
    const int f = fb >> 9;        // / 512
    const int b = fb & 511;
    const int tid = threadIdx.x;

    const float* src = x + b * NPIX;
    for (int i = tid; i < NPIX; i += 256) img[i] = src[i];
    if (tid < 49) wsh[tid] = w[(f * 2 + 0) * 49 + tid];
    __syncthreads();

    const float a = alpha[f * 2 + 0];

    for (int p = tid; p < NPIX; p += 256) {
        const int i = p / HW;
        const int j = p - i * HW;
        float num = 0.f, den = 0.f;
#pragma unroll
        for (int di = 0; di < KF; ++di) {
            const int ii = i + di - 3;
            const bool rowok = ((unsigned)ii < (unsigned)HW);
            const int iic = min(max(ii, 0), HW - 1);
#pragma unroll
            for (int dj = 0; dj < KF; ++dj) {
                const int jj = j + dj - 3;
                const bool ok = rowok && ((unsigned)jj < (unsigned)HW);
                const int jjc = min(max(jj, 0), HW - 1);
                const float v = ok ? img[iic * HW + jjc] : 0.f;
                const float z = v + wsh[di * KF + dj];
                const float e = __expf(a * z);
                num = fmaf(z, e, num);
                den += e;
            }
        }
        y1[fb * NPIX + p] = num / den;
    }
}

// ---------------------------------------------------------------------------
// SMorph stage 1 + double 2x2 avg pool (= 4x4 mean) -> feat[b, f*49 + p]
// ---------------------------------------------------------------------------
__global__ __launch_bounds__(256) void smorph2_pool_kernel(
    const float* __restrict__ y1,     // [8, 512, 784]
    const float* __restrict__ w,      // [8, 2, 49]
    const float* __restrict__ alpha,  // [8, 2]
    float* __restrict__ feat)         // [512, 392]
{
    __shared__ float img[NPIX];
    __shared__ float outp[NPIX];
    __shared__ float wsh[49];
    const int fb = blockIdx.x;
    const int f = fb >> 9;
    const int b = fb & 511;
    const int tid = threadIdx.x;

    const float* src = y1 + fb * NPIX;
    for (int i = tid; i < NPIX; i += 256) img[i] = src[i];
    if (tid < 49) wsh[tid] = w[(f * 2 + 1) * 49 + tid];
    __syncthreads();

    const float a = alpha[f * 2 + 1];

    for (int p = tid; p < NPIX; p += 256) {
        const int i = p / HW;
        const int j = p - i * HW;
        float num = 0.f, den = 0.f;
#pragma unroll
        for (int di = 0; di < KF; ++di) {
            const int ii = i + di - 3;
            const bool rowok = ((unsigned)ii < (unsigned)HW);
            const int iic = min(max(ii, 0), HW - 1);
#pragma unroll
            for (int dj = 0; dj < KF; ++dj) {
                const int jj = j + dj - 3;
                const bool ok = rowok && ((unsigned)jj < (unsigned)HW);
                const int jjc = min(max(jj, 0), HW - 1);
                const float v = ok ? img[iic * HW + jjc] : 0.f;
                const float z = v + wsh[di * KF + dj];
                const float e = __expf(a * z);
                num = fmaf(z, e, num);
                den += e;
            }
        }
        outp[p] = num / den;
    }
    __syncthreads();

    // 4x4 mean pool -> 7x7, write feat[b, f*49 + t]
    if (tid < 49) {
        const int pi = tid / 7;
        const int pj = tid - pi * 7;
        float s = 0.f;
#pragma unroll
        for (int di = 0; di < 4; ++di)
#pragma unroll
            for (int dj = 0; dj < 4; ++dj)
                s += outp[(pi * 4 + di) * HW + (pj * 4 + dj)];
        feat[b * 392 + f * 49 + tid] = s * (1.f / 16.f);
    }
}

// ---------------------------------------------------------------------------
// MLP: 392 -> 120 -> 84 -> 10, sigmoid each layer. One block per batch row.
// ---------------------------------------------------------------------------
__global__ __launch_bounds__(128) void mlp_kernel(
    const float* __restrict__ feat,  // [512, 392]
    const float* __restrict__ W1, const float* __restrict__ b1,   // [120,392],[120]
    const float* __restrict__ W2, const float* __restrict__ b2,   // [84,120],[84]
    const float* __restrict__ W3, const float* __restrict__ b3,   // [10,84],[10]
    float* __restrict__ out)         // [512, 10]
{
    __shared__ float fsh[392];
    __shared__ float h1[120];
    __shared__ float h2[84];
    const int b = blockIdx.x;
    const int tid = threadIdx.x;

    for (int i = tid; i < 392; i += 128) fsh[i] = feat[b * 392 + i];
    __syncthreads();

    if (tid < 120) {
        const float* wr = W1 + tid * 392;
        float s = b1[tid];
        for (int k = 0; k < 392; ++k) s = fmaf(fsh[k], wr[k], s);
        h1[tid] = 1.f / (1.f + __expf(-s));
    }
    __syncthreads();

    if (tid < 84) {
        const float* wr = W2 + tid * 120;
        float s = b2[tid];
        for (int k = 0; k < 120; ++k) s = fmaf(h1[k], wr[k], s);
        h2[tid] = 1.f / (1.f + __expf(-s));
    }
    __syncthreads();

    if (tid < 10) {
        const float* wr = W3 + tid * 84;
        float s = b3[tid];
        for (int k = 0; k < 84; ++k) s = fmaf(h2[k], wr[k], s);
        out[b * 10 + tid] = 1.f / (1.f + __expf(-s));
    }
}

extern "C" void kernel_launch(void* const* d_in, const int* in_sizes, int n_in,
                              void* d_out, int out_size, void* d_ws, size_t ws_size,
                              hipStream_t stream) {
    const float* x  = (const float*)d_in[0];
    const float* sw = (const float*)d_in[1];
    const float* sa = (const float*)d_in[2];
    const float* W1 = (const float*)d_in[3];
    const float* b1 = (const float*)d_in[4];
    const float* W2 = (const float*)d_in[5];
    const float* b2 = (const float*)d_in[6];
    const float* W3 = (const float*)d_in[7];
    const float* b3 = (const float*)d_in[8];
    float* out = (float*)d_out;

    float* ws   = (float*)d_ws;
    float* y1   = ws;                        // 8*512*784 = 3,211,264 floats
    float* feat = ws + (size_t)NF * NB * NPIX;  // 512*392  =   200,704 floats

    smorph1_kernel<<<NF * NB, 256, 0, stream>>>(x, sw, sa, y1);
    smorph2_pool_kernel<<<NF * NB, 256, 0, stream>>>(y1, sw, sa, feat);
    mlp_kernel<<<NB, 128, 0, stream>>>(feat, W1, b1, W2, b2, W3, b3, out);
}

// Round 2
// 132.032 us; speedup vs baseline: 1.3637x; 1.3637x over previous
//
#include <hip/hip_runtime.h>

#define KF 7
#define HW 28
#define NPIX 784
#define NB 512
#define NF 8
#define PADW 35   // padded row stride (float2 units); 34 cols used + 1 pad
#define PADH 34   // rows -3..30

// ---------------------------------------------------------------------------
// Weight table setup: wtab[f*2+s][t] = (ew, qw) = (exp(a*w), w*exp(a*w))
// ---------------------------------------------------------------------------
__global__ void setup_wtab(const float* __restrict__ w,      // [8,2,49]
                           const float* __restrict__ alpha,  // [8,2]
                           float2* __restrict__ wtab)        // [16,49]
{
    int idx = blockIdx.x * 256 + threadIdx.x;
    if (idx < 16 * 49) {
        int fs = idx / 49;
        int t  = idx - fs * 49;
        float a  = alpha[fs];
        float wv = w[fs * 49 + t];
        float e  = __expf(a * wv);
        wtab[idx] = make_float2(e, wv * e);
    }
}

// ---------------------------------------------------------------------------
// 7x7 triple-correlation on a padded evpv image in LDS.
// Thread handles a vertical strip of 4 output pixels (rows 4g..4g+3, col j).
// out[r] = (sum pv*ew + sum ev*qw) / (sum ev*ew)
// ---------------------------------------------------------------------------
__device__ __forceinline__ void conv49(const float2* sbuf,              // LDS padded
                                       const float2* __restrict__ wt,   // global, uniform
                                       int g, int j, float out[4])
{
    float sA[4] = {0.f, 0.f, 0.f, 0.f};  // sum pv*ew
    float sB[4] = {0.f, 0.f, 0.f, 0.f};  // sum ev*qw
    float sD[4] = {0.f, 0.f, 0.f, 0.f};  // sum ev*ew
#pragma unroll
    for (int rr = 0; rr < 10; ++rr) {
        float2 tap[7];
        const float2* row = sbuf + (4 * g + rr) * PADW + j;
#pragma unroll
        for (int t = 0; t < 7; ++t) tap[t] = row[t];
#pragma unroll
        for (int r = 0; r < 4; ++r) {
            if (r > rr || rr - r > 6) continue;   // folds at compile time
            const int di = rr - r;
#pragma unroll
            for (int t = 0; t < 7; ++t) {
                float2 wv = wt[di * 7 + t];
                sD[r] = fmaf(tap[t].x, wv.x, sD[r]);
                sA[r] = fmaf(tap[t].y, wv.x, sA[r]);
                sB[r] = fmaf(tap[t].x, wv.y, sB[r]);
            }
        }
    }
#pragma unroll
    for (int r = 0; r < 4; ++r)
        out[r] = (sA[r] + sB[r]) * __builtin_amdgcn_rcpf(sD[r]);
}

// ---------------------------------------------------------------------------
// Fused: smorph(stage0) -> smorph(stage1) -> 4x4 mean pool -> feat
// One block per (f,b) image.
// ---------------------------------------------------------------------------
__global__ __launch_bounds__(256) void smorph_fused_kernel(
    const float* __restrict__ x,       // [512,784]
    const float2* __restrict__ wtab,   // [16,49]
    const float* __restrict__ alpha,   // [8,2]
    float* __restrict__ feat)          // [512,392]
{
    __shared__ float2 buf1[PADH * PADW];
    __shared__ float2 buf2[PADH * PADW];
    __shared__ float  outp[NPIX];

    const int fb  = blockIdx.x;
    const int f   = fb >> 9;
    const int b   = fb & 511;
    const int tid = threadIdx.x;

    const float a1 = alpha[f * 2 + 0];
    const float a2 = alpha[f * 2 + 1];
    const float2* wt1 = wtab + (f * 2 + 0) * 49;
    const float2* wt2 = wtab + (f * 2 + 1) * 49;
    const float* src = x + b * NPIX;

    // init padded evpv for stage 0; borders of both buffers get (ev=1, pv=0)
    for (int idx = tid; idx < PADH * PADW; idx += 256) {
        int pi = idx / PADW;
        int pj = idx - pi * PADW;
        bool interior = (pi >= 3 && pi < 31 && pj >= 3 && pj < 31);
        if (interior) {
            float v = src[(pi - 3) * HW + (pj - 3)];
            float e = __expf(a1 * v);
            buf1[idx] = make_float2(e, v * e);
        } else {
            buf1[idx] = make_float2(1.f, 0.f);
            buf2[idx] = make_float2(1.f, 0.f);
        }
    }
    __syncthreads();

    float o[4];
    int g = 0, j = 0;
    if (tid < 196) { g = tid / 28; j = tid - g * 28; }

    if (tid < 196) {
        conv49(buf1, wt1, g, j, o);
#pragma unroll
        for (int r = 0; r < 4; ++r) {
            float e = __expf(a2 * o[r]);
            buf2[(4 * g + r + 3) * PADW + (j + 3)] = make_float2(e, o[r] * e);
        }
    }
    __syncthreads();

    if (tid < 196) {
        conv49(buf2, wt2, g, j, o);
#pragma unroll
        for (int r = 0; r < 4; ++r)
            outp[(4 * g + r) * HW + j] = o[r];
    }
    __syncthreads();

    // 4x4 mean pool -> 7x7
    if (tid < 49) {
        int pi = tid / 7;
        int pj = tid - pi * 7;
        float s = 0.f;
#pragma unroll
        for (int di = 0; di < 4; ++di)
#pragma unroll
            for (int dj = 0; dj < 4; ++dj)
                s += outp[(pi * 4 + di) * HW + (pj * 4 + dj)];
        feat[b * 392 + f * 49 + tid] = s * 0.0625f;
    }
}

// ---------------------------------------------------------------------------
// MLP: 392 -> 120 -> 84 -> 10, sigmoid each. 4 batch rows per block.
// ---------------------------------------------------------------------------
__device__ __forceinline__ float sigmoidf_(float s) {
    return __builtin_amdgcn_rcpf(1.f + __expf(-s));
}

__global__ __launch_bounds__(256) void mlp_kernel(
    const float* __restrict__ feat,  // [512,392]
    const float* __restrict__ W1, const float* __restrict__ b1,
    const float* __restrict__ W2, const float* __restrict__ b2,
    const float* __restrict__ W3, const float* __restrict__ b3,
    float* __restrict__ out)         // [512,10]
{
    __shared__ float fsh[4 * 392];
    __shared__ float h1[4][120];
    __shared__ float h2[4][84];
    const int r0  = blockIdx.x * 4;
    const int tid = threadIdx.x;

    for (int q = tid; q < 4 * 392; q += 256) fsh[q] = feat[r0 * 392 + q];
    __syncthreads();

    if (tid < 240) {
        int n = tid % 120;
        int h = tid / 120;             // 0/1 -> rows 2h, 2h+1
        const float4* wr = (const float4*)(W1 + n * 392);
        const float4* f0 = (const float4*)(fsh + (2 * h) * 392);
        const float4* f1 = (const float4*)(fsh + (2 * h + 1) * 392);
        float a0 = 0.f, a1 = 0.f;
        for (int k = 0; k < 98; ++k) {
            float4 wv = wr[k];
            float4 x0 = f0[k];
            float4 x1 = f1[k];
            a0 = fmaf(wv.x, x0.x, fmaf(wv.y, x0.y, fmaf(wv.z, x0.z, fmaf(wv.w, x0.w, a0))));
            a1 = fmaf(wv.x, x1.x, fmaf(wv.y, x1.y, fmaf(wv.z, x1.z, fmaf(wv.w, x1.w, a1))));
        }
        float bb = b1[n];
        h1[2 * h][n]     = sigmoidf_(a0 + bb);
        h1[2 * h + 1][n] = sigmoidf_(a1 + bb);
    }
    __syncthreads();

    if (tid < 168) {
        int n = tid % 84;
        int h = tid / 84;
        const float4* wr = (const float4*)(W2 + n * 120);
        const float4* x0 = (const float4*)(h1[2 * h]);
        const float4* x1 = (const float4*)(h1[2 * h + 1]);
        float a0 = 0.f, a1 = 0.f;
        for (int k = 0; k < 30; ++k) {
            float4 wv = wr[k];
            float4 v0 = x0[k];
            float4 v1 = x1[k];
            a0 = fmaf(wv.x, v0.x, fmaf(wv.y, v0.y, fmaf(wv.z, v0.z, fmaf(wv.w, v0.w, a0))));
            a1 = fmaf(wv.x, v1.x, fmaf(wv.y, v1.y, fmaf(wv.z, v1.z, fmaf(wv.w, v1.w, a1))));
        }
        float bb = b2[n];
        h2[2 * h][n]     = sigmoidf_(a0 + bb);
        h2[2 * h + 1][n] = sigmoidf_(a1 + bb);
    }
    __syncthreads();

    if (tid < 40) {
        int n = tid % 10;
        int r = tid / 10;
        const float4* wr = (const float4*)(W3 + n * 84);
        const float4* xr = (const float4*)(h2[r]);
        float a0 = 0.f;
        for (int k = 0; k < 21; ++k) {
            float4 wv = wr[k];
            float4 v0 = xr[k];
            a0 = fmaf(wv.x, v0.x, fmaf(wv.y, v0.y, fmaf(wv.z, v0.z, fmaf(wv.w, v0.w, a0))));
        }
        out[(r0 + r) * 10 + n] = sigmoidf_(a0 + b3[n]);
    }
}

extern "C" void kernel_launch(void* const* d_in, const int* in_sizes, int n_in,
                              void* d_out, int out_size, void* d_ws, size_t ws_size,
                              hipStream_t stream) {
    const float* x  = (const float*)d_in[0];
    const float* sw = (const float*)d_in[1];
    const float* sa = (const float*)d_in[2];
    const float* W1 = (const float*)d_in[3];
    const float* b1 = (const float*)d_in[4];
    const float* W2 = (const float*)d_in[5];
    const float* b2 = (const float*)d_in[6];
    const float* W3 = (const float*)d_in[7];
    const float* b3 = (const float*)d_in[8];
    float* out = (float*)d_out;

    float2* wtab = (float2*)d_ws;                       // 16*49 float2 = 6272 B
    float*  feat = (float*)d_ws + 2 * 16 * 49;          // 512*392 floats

    setup_wtab<<<4, 256, 0, stream>>>(sw, sa, wtab);
    smorph_fused_kernel<<<NF * NB, 256, 0, stream>>>(x, wtab, sa, feat);
    mlp_kernel<<<NB / 4, 256, 0, stream>>>(feat, W1, b1, W2, b2, W3, b3, out);
}

// Round 3
// 131.965 us; speedup vs baseline: 1.3644x; 1.0005x over previous
//
#include <hip/hip_runtime.h>

#define HW 28
#define NPIX 784
#define NB 512
#define NF 8
#define PADW 35           // padded row stride in float2
#define PADH 34           // rows -3..30
#define IMG_F2 (PADH * PADW)   // 1190 float2 = 9520 B per buffer

// ---------------------------------------------------------------------------
// wtab[f*2+s][t] = (ew, qw) = (exp(a*w), w*exp(a*w))
// ---------------------------------------------------------------------------
__global__ void setup_wtab(const float* __restrict__ w,
                           const float* __restrict__ alpha,
                           float2* __restrict__ wtab)
{
    int idx = blockIdx.x * 256 + threadIdx.x;
    if (idx < 16 * 49) {
        int fs = idx / 49;
        int t  = idx - fs * 49;
        float a  = alpha[fs];
        float wv = w[fs * 49 + t];
        float e  = __expf(a * wv);
        wtab[idx] = make_float2(e, wv * e);
    }
}

// ---------------------------------------------------------------------------
// Strip-7 rolling 7x7 triple-correlation: thread computes 7 outputs in a
// column (rows R0..R0+6, col j), reading 13 rows x 7 taps = 91 b64 for
// 7 outputs (13 reads/output vs 17.5 for strip-4).
// out[r] = (sum pv*ew + sum ev*qw) / (sum ev*ew)
// ---------------------------------------------------------------------------
__device__ __forceinline__ void conv7(const float2* sbuf,
                                      const float2* __restrict__ wt,  // uniform
                                      int R0, int j, float out[7])
{
    float sA[7], sB[7], sD[7];
#pragma unroll
    for (int r = 0; r < 7; ++r) { sA[r] = 0.f; sB[r] = 0.f; sD[r] = 0.f; }
#pragma unroll
    for (int rr = 0; rr < 13; ++rr) {
        float2 tap[7];
        const float2* row = sbuf + (R0 + rr) * PADW + j;
#pragma unroll
        for (int t = 0; t < 7; ++t) tap[t] = row[t];
#pragma unroll
        for (int r = 0; r < 7; ++r) {
            if (r > rr || rr - r > 6) continue;   // compile-time fold
            const float2* wrow = wt + (rr - r) * 7;
#pragma unroll
            for (int t = 0; t < 7; ++t) {
                float2 wv = wrow[t];
                sD[r] = fmaf(tap[t].x, wv.x, sD[r]);
                sA[r] = fmaf(tap[t].y, wv.x, sA[r]);
                sB[r] = fmaf(tap[t].x, wv.y, sB[r]);
            }
        }
    }
#pragma unroll
    for (int r = 0; r < 7; ++r)
        out[r] = (sA[r] + sB[r]) * __builtin_amdgcn_rcpf(sD[r]);
}

// ---------------------------------------------------------------------------
// Fused smorph x2 + 4x4 mean pool. 2 images per block (same filter f, so
// weight reads stay scalar-uniform). LDS 38 KB -> 4 blocks/CU.
// ---------------------------------------------------------------------------
__global__ __launch_bounds__(256, 4) void smorph_fused_kernel(
    const float* __restrict__ x,       // [512,784]
    const float2* __restrict__ wtab,   // [16,49]
    const float* __restrict__ alpha,   // [8,2]
    float* __restrict__ feat)          // [512,392]
{
    __shared__ float2 evpv1[2][IMG_F2];
    __shared__ float2 evpv2[2][IMG_F2];

    const int bx  = blockIdx.x;        // 2048 blocks
    const int f   = bx >> 8;
    const int bp  = bx & 255;          // image pair
    const int tid = threadIdx.x;

    const float a1 = alpha[f * 2 + 0];
    const float a2 = alpha[f * 2 + 1];
    const float2* wt1 = wtab + (f * 2 + 0) * 49;
    const float2* wt2 = wtab + (f * 2 + 1) * 49;

    // init evpv1 interior from x, borders of both buffers to (ev=1, pv=0)
#pragma unroll
    for (int img = 0; img < 2; ++img) {
        const float* src = x + (size_t)(bp * 2 + img) * NPIX;
        for (int idx = tid; idx < IMG_F2; idx += 256) {
            int pi = idx / PADW;
            int pj = idx - pi * PADW;
            float2 val = make_float2(1.f, 0.f);
            if (pi >= 3 && pi < 31 && pj >= 3 && pj < 31) {
                float v = src[(pi - 3) * HW + (pj - 3)];
                float e = __expf(a1 * v);
                val = make_float2(e, v * e);
            } else {
                evpv2[img][idx] = make_float2(1.f, 0.f);
            }
            evpv1[img][idx] = val;
        }
    }
    __syncthreads();

    const bool act = (tid < 224);
    int img = 0, s = 0, j = 0;
    if (act) {
        img = tid / 112;
        int t = tid - img * 112;
        s = t / 28;
        j = t - s * 28;
    }
    const int R0 = s * 7;

    float o[7];
    if (act) {
        conv7(evpv1[img], wt1, R0, j, o);
#pragma unroll
        for (int r = 0; r < 7; ++r) {
            float e = __expf(a2 * o[r]);
            evpv2[img][(R0 + r + 3) * PADW + (j + 3)] = make_float2(e, o[r] * e);
        }
    }
    __syncthreads();

    // conv2 reads evpv2; outputs alias into evpv1 (done with it; barrier above)
    if (act) {
        conv7(evpv2[img], wt2, R0, j, o);
        float* outp = (float*)&evpv1[img][0];
#pragma unroll
        for (int r = 0; r < 7; ++r)
            outp[(R0 + r) * HW + j] = o[r];
    }
    __syncthreads();

    // 4x4 mean pool -> feat[b, f*49 + t]
    if (tid < 98) {
        int im = tid / 49;
        int t  = tid - im * 49;
        int pi = t / 7;
        int pj = t - pi * 7;
        const float* op = (const float*)&evpv1[im][0];
        float sum = 0.f;
#pragma unroll
        for (int di = 0; di < 4; ++di)
#pragma unroll
            for (int dj = 0; dj < 4; ++dj)
                sum += op[(pi * 4 + di) * HW + (pj * 4 + dj)];
        feat[(size_t)(bp * 2 + im) * 392 + f * 49 + t] = sum * 0.0625f;
    }
}

// ---------------------------------------------------------------------------
// MLP 392->120->84->10, sigmoid. One block per batch row; each dot split
// across lanes with component-parallel accumulators + shuffle reduce.
// ---------------------------------------------------------------------------
__device__ __forceinline__ float sigmoidf_(float s) {
    return __builtin_amdgcn_rcpf(1.f + __expf(-s));
}

__global__ __launch_bounds__(256) void mlp_kernel(
    const float* __restrict__ feat,
    const float* __restrict__ W1, const float* __restrict__ b1,
    const float* __restrict__ W2, const float* __restrict__ b2,
    const float* __restrict__ W3, const float* __restrict__ b3,
    float* __restrict__ out)
{
    __shared__ __align__(16) float fsh[392];
    __shared__ __align__(16) float h1[120];
    __shared__ __align__(16) float h2[84];
    const int b   = blockIdx.x;
    const int tid = threadIdx.x;

    if (tid < 98)
        ((float4*)fsh)[tid] = ((const float4*)(feat + (size_t)b * 392))[tid];
    __syncthreads();

    // Layer 1: 120 neurons x 2 lanes, 49 float4 each (98 total)
    if (tid < 240) {
        int n = tid >> 1, h = tid & 1;
        const float4* wr = (const float4*)(W1 + n * 392);
        const float4* fv = (const float4*)fsh;
        float c0 = 0.f, c1 = 0.f, c2 = 0.f, c3 = 0.f;
#pragma unroll 7
        for (int k = h; k < 98; k += 2) {
            float4 w = wr[k];
            float4 v = fv[k];
            c0 = fmaf(w.x, v.x, c0);
            c1 = fmaf(w.y, v.y, c1);
            c2 = fmaf(w.z, v.z, c2);
            c3 = fmaf(w.w, v.w, c3);
        }
        float acc = (c0 + c1) + (c2 + c3);
        acc += __shfl_xor(acc, 1);
        if (h == 0) h1[n] = sigmoidf_(acc + b1[n]);
    }
    __syncthreads();

    // Layer 2: 84 neurons x 2 lanes, 15 float4 each (30 total)
    if (tid < 168) {
        int n = tid >> 1, h = tid & 1;
        const float4* wr = (const float4*)(W2 + n * 120);
        const float4* hv = (const float4*)h1;
        float c0 = 0.f, c1 = 0.f, c2 = 0.f, c3 = 0.f;
#pragma unroll
        for (int k = h; k < 30; k += 2) {
            float4 w = wr[k];
            float4 v = hv[k];
            c0 = fmaf(w.x, v.x, c0);
            c1 = fmaf(w.y, v.y, c1);
            c2 = fmaf(w.z, v.z, c2);
            c3 = fmaf(w.w, v.w, c3);
        }
        float acc = (c0 + c1) + (c2 + c3);
        acc += __shfl_xor(acc, 1);
        if (h == 0) h2[n] = sigmoidf_(acc + b2[n]);
    }
    __syncthreads();

    // Layer 3: 10 neurons x 4 lanes, 21 float4 split 6/5/5/5
    if (tid < 40) {
        int n = tid >> 2, q = tid & 3;
        const float4* wr = (const float4*)(W3 + n * 84);
        const float4* hv = (const float4*)h2;
        float c0 = 0.f, c1 = 0.f, c2 = 0.f, c3 = 0.f;
        for (int k = q; k < 21; k += 4) {
            float4 w = wr[k];
            float4 v = hv[k];
            c0 = fmaf(w.x, v.x, c0);
            c1 = fmaf(w.y, v.y, c1);
            c2 = fmaf(w.z, v.z, c2);
            c3 = fmaf(w.w, v.w, c3);
        }
        float acc = (c0 + c1) + (c2 + c3);
        acc += __shfl_xor(acc, 1);
        acc += __shfl_xor(acc, 2);
        if (q == 0) out[(size_t)b * 10 + n] = sigmoidf_(acc + b3[n]);
    }
}

extern "C" void kernel_launch(void* const* d_in, const int* in_sizes, int n_in,
                              void* d_out, int out_size, void* d_ws, size_t ws_size,
                              hipStream_t stream) {
    const float* x  = (const float*)d_in[0];
    const float* sw = (const float*)d_in[1];
    const float* sa = (const float*)d_in[2];
    const float* W1 = (const float*)d_in[3];
    const float* b1 = (const float*)d_in[4];
    const float* W2 = (const float*)d_in[5];
    const float* b2 = (const float*)d_in[6];
    const float* W3 = (const float*)d_in[7];
    const float* b3 = (const float*)d_in[8];
    float* out = (float*)d_out;

    float2* wtab = (float2*)d_ws;                  // 16*49 float2 = 6272 B
    float*  feat = (float*)d_ws + 2 * 16 * 49;     // 512*392 floats

    setup_wtab<<<4, 256, 0, stream>>>(sw, sa, wtab);
    smorph_fused_kernel<<<2048, 256, 0, stream>>>(x, wtab, sa, feat);
    mlp_kernel<<<NB, 256, 0, stream>>>(feat, W1, b1, W2, b2, W3, b3, out);
}